// Round 1
// baseline (254.999 us; speedup 1.0000x reference)
//
#include <hip/hip_runtime.h>

#define NNODE 2048
#define DD    512
#define HHID  256
#define LLAT  16
#define H2    32   // 2L

typedef __attribute__((ext_vector_type(8))) short  short8;
typedef __attribute__((ext_vector_type(4))) float  f32x4;

__device__ __forceinline__ unsigned short f2bf(float x) {
    unsigned int u = __float_as_uint(x);
    unsigned int r = (u + 0x7fffu + ((u >> 16) & 1u)) >> 16;  // RNE
    return (unsigned short)r;
}

// ---------------- T1: XWt[h][n] = sum_d W1[h][d] * X[n][d]  (fp32, bf16 out) ----
__global__ __launch_bounds__(256) void t1_xw(const float* __restrict__ W1,
                                             const float* __restrict__ X,
                                             unsigned short* __restrict__ XWt) {
    __shared__ float As[64][17];
    __shared__ float Bs[64][17];
    const int tid = threadIdx.x;
    const int n0 = blockIdx.x * 64;
    const int h0 = blockIdx.y * 64;
    const int tx = tid & 15, ty = tid >> 4;
    const int lr = tid >> 2;          // 0..63
    const int lc = (tid & 3) * 4;     // 0,4,8,12
    float acc[4][4] = {};
    for (int d0 = 0; d0 < DD; d0 += 16) {
        float4 av = *(const float4*)(W1 + (size_t)(h0 + lr) * DD + d0 + lc);
        float4 bv = *(const float4*)(X  + (size_t)(n0 + lr) * DD + d0 + lc);
        As[lr][lc + 0] = av.x; As[lr][lc + 1] = av.y; As[lr][lc + 2] = av.z; As[lr][lc + 3] = av.w;
        Bs[lr][lc + 0] = bv.x; Bs[lr][lc + 1] = bv.y; Bs[lr][lc + 2] = bv.z; Bs[lr][lc + 3] = bv.w;
        __syncthreads();
        #pragma unroll
        for (int d = 0; d < 16; ++d) {
            float ar[4], br[4];
            #pragma unroll
            for (int i = 0; i < 4; ++i) ar[i] = As[ty * 4 + i][d];
            #pragma unroll
            for (int j = 0; j < 4; ++j) br[j] = Bs[tx * 4 + j][d];
            #pragma unroll
            for (int i = 0; i < 4; ++i)
                #pragma unroll
                for (int j = 0; j < 4; ++j) acc[i][j] = fmaf(ar[i], br[j], acc[i][j]);
        }
        __syncthreads();
    }
    #pragma unroll
    for (int i = 0; i < 4; ++i)
        #pragma unroll
        for (int j = 0; j < 4; ++j)
            XWt[(size_t)(h0 + ty * 4 + i) * NNODE + n0 + tx * 4 + j] = f2bf(acc[i][j]);
}

// ---------------- T2: Hh = leaky(A @ XW + b1)   MFMA bf16, 64x64 tile ------------
__global__ __launch_bounds__(256) void t2_gemm(const float* __restrict__ A,
                                               const unsigned short* __restrict__ XWt,
                                               const float* __restrict__ b1,
                                               float* __restrict__ Hh) {
    __shared__ __align__(16) unsigned short Ab[64][40];  // +8 bf16 pad
    __shared__ __align__(16) unsigned short Bb[64][40];
    const int tid = threadIdx.x;
    const int m0 = blockIdx.x * 64;
    const int n0 = blockIdx.y * 64;
    const int lane = tid & 63, wave = tid >> 6;
    const int wm = wave >> 1, wn = wave & 1;
    const int lm = lane & 15, lk = (lane >> 4) * 8;
    const int br_ = tid >> 2, bc = (tid & 3) * 8;   // B staging
    f32x4 acc[2][2] = {};
    for (int kk = 0; kk < NNODE; kk += 32) {
        #pragma unroll
        for (int s = 0; s < 2; ++s) {               // A staging: fp32 -> bf16 inline
            int f = tid + s * 256;
            int row = f >> 3, c = f & 7;
            float4 v = *(const float4*)(A + (size_t)(m0 + row) * NNODE + kk + c * 4);
            short4 h4;
            h4.x = (short)f2bf(v.x); h4.y = (short)f2bf(v.y);
            h4.z = (short)f2bf(v.z); h4.w = (short)f2bf(v.w);
            *(short4*)&Ab[row][c * 4] = h4;
        }
        {
            uint4 v = *(const uint4*)(XWt + (size_t)(n0 + br_) * NNODE + kk + bc);
            *(uint4*)&Bb[br_][bc] = v;
        }
        __syncthreads();
        short8 a0 = *(const short8*)&Ab[wm * 32 + lm][lk];
        short8 a1 = *(const short8*)&Ab[wm * 32 + 16 + lm][lk];
        short8 b0 = *(const short8*)&Bb[wn * 32 + lm][lk];
        short8 b1v = *(const short8*)&Bb[wn * 32 + 16 + lm][lk];
        acc[0][0] = __builtin_amdgcn_mfma_f32_16x16x32_bf16(a0, b0,  acc[0][0], 0, 0, 0);
        acc[0][1] = __builtin_amdgcn_mfma_f32_16x16x32_bf16(a0, b1v, acc[0][1], 0, 0, 0);
        acc[1][0] = __builtin_amdgcn_mfma_f32_16x16x32_bf16(a1, b0,  acc[1][0], 0, 0, 0);
        acc[1][1] = __builtin_amdgcn_mfma_f32_16x16x32_bf16(a1, b1v, acc[1][1], 0, 0, 0);
        __syncthreads();
    }
    #pragma unroll
    for (int mi = 0; mi < 2; ++mi)
        #pragma unroll
        for (int ni = 0; ni < 2; ++ni)
            #pragma unroll
            for (int r = 0; r < 4; ++r) {
                int row = m0 + wm * 32 + mi * 16 + (lane >> 4) * 4 + r;
                int col = n0 + wn * 32 + ni * 16 + lm;
                float v = acc[mi][ni][r] + b1[col];
                v = v >= 0.f ? v : 0.01f * v;
                Hh[(size_t)row * HHID + col] = v;
            }
}

// ---------------- T3: Gt[j][n] = sum_d Hh[n][d] * Wcat[j][d]  (bf16 out) ---------
__global__ __launch_bounds__(256) void t3_g(const float* __restrict__ Hh,
                                            const float* __restrict__ Wmu,
                                            const float* __restrict__ Wlv,
                                            unsigned short* __restrict__ Gt) {
    int idx = blockIdx.x * 256 + threadIdx.x;  // 0..65535
    int n = idx >> 5, j = idx & 31;
    const float4* h4 = (const float4*)(Hh + (size_t)n * HHID);
    const float4* w4 = (const float4*)(j < 16 ? (Wmu + (size_t)j * HHID)
                                              : (Wlv + (size_t)(j - 16) * HHID));
    float acc = 0.f;
    #pragma unroll 8
    for (int d = 0; d < HHID / 4; ++d) {
        float4 a = h4[d], b = w4[d];
        acc += a.x * b.x + a.y * b.y + a.z * b.z + a.w * b.w;
    }
    Gt[(size_t)j * NNODE + n] = f2bf(acc);
}

// ---------------- T4: M4 = A @ G  (MFMA, split-K=8, atomic accumulate) -----------
__global__ __launch_bounds__(256) void t4_gemm(const float* __restrict__ A,
                                               const unsigned short* __restrict__ Gt,
                                               float* __restrict__ M4) {
    __shared__ __align__(16) unsigned short Ab[64][40];
    __shared__ __align__(16) unsigned short Bb[32][40];
    const int tid = threadIdx.x;
    const int m0 = blockIdx.x * 64;
    const int ks = blockIdx.y;
    const int lane = tid & 63, wave = tid >> 6;
    const int lm = lane & 15, lk = (lane >> 4) * 8;
    f32x4 acc[2] = {};
    for (int it = 0; it < 8; ++it) {
        int kk = ks * 256 + it * 32;
        #pragma unroll
        for (int s = 0; s < 2; ++s) {
            int f = tid + s * 256;
            int row = f >> 3, c = f & 7;
            float4 v = *(const float4*)(A + (size_t)(m0 + row) * NNODE + kk + c * 4);
            short4 h4;
            h4.x = (short)f2bf(v.x); h4.y = (short)f2bf(v.y);
            h4.z = (short)f2bf(v.z); h4.w = (short)f2bf(v.w);
            *(short4*)&Ab[row][c * 4] = h4;
        }
        if (tid < 128) {
            int row = tid >> 2, c = (tid & 3) * 8;
            uint4 v = *(const uint4*)(Gt + (size_t)row * NNODE + kk + c);
            *(uint4*)&Bb[row][c] = v;
        }
        __syncthreads();
        short8 a  = *(const short8*)&Ab[wave * 16 + lm][lk];
        short8 b0 = *(const short8*)&Bb[lm][lk];
        short8 b1 = *(const short8*)&Bb[16 + lm][lk];
        acc[0] = __builtin_amdgcn_mfma_f32_16x16x32_bf16(a, b0, acc[0], 0, 0, 0);
        acc[1] = __builtin_amdgcn_mfma_f32_16x16x32_bf16(a, b1, acc[1], 0, 0, 0);
        __syncthreads();
    }
    #pragma unroll
    for (int ni = 0; ni < 2; ++ni)
        #pragma unroll
        for (int r = 0; r < 4; ++r) {
            int row = m0 + wave * 16 + (lane >> 4) * 4 + r;
            int col = ni * 16 + lm;
            atomicAdd(&M4[(size_t)row * H2 + col], acc[ni][r]);
        }
}

// ---------------- T5: mu/logvar out, Z, P' = Z@Wd1[:,:L]^T + bd1, Q --------------
__global__ __launch_bounds__(256) void t5_z(const float* __restrict__ M4,
                                            const float* __restrict__ bmu,
                                            const float* __restrict__ blv,
                                            const float* __restrict__ eps,
                                            const float* __restrict__ Wd1,
                                            const float* __restrict__ bd1,
                                            float* __restrict__ out_mu,
                                            float* __restrict__ out_lv,
                                            float* __restrict__ Pp,
                                            float* __restrict__ Qq) {
    __shared__ float Zs[64][16];
    const int tid = threadIdx.x;
    const int n0 = blockIdx.x * 64;
    #pragma unroll
    for (int p = 0; p < 4; ++p) {
        int idx = tid + p * 256;            // 0..1023
        int nl = idx >> 4, l = idx & 15;
        int n = n0 + nl;
        float m  = M4[(size_t)n * H2 + l]      + bmu[l];
        float lv = M4[(size_t)n * H2 + 16 + l] + blv[l];
        out_mu[(size_t)n * LLAT + l] = m;
        out_lv[(size_t)n * LLAT + l] = lv;
        Zs[nl][l] = m + eps[(size_t)n * LLAT + l] * __expf(0.5f * lv);
    }
    __syncthreads();
    #pragma unroll
    for (int p = 0; p < 8; ++p) {
        int idx = tid + p * 256;            // 0..2047
        int nl = idx >> 5, o = idx & 31;
        int n = n0 + nl;
        float ap = bd1[o], aq = 0.f;
        #pragma unroll
        for (int l = 0; l < 16; ++l) {
            float z = Zs[nl][l];
            ap = fmaf(z, Wd1[o * H2 + l],      ap);
            aq = fmaf(z, Wd1[o * H2 + 16 + l], aq);
        }
        Pp[(size_t)n * H2 + o] = ap;
        Qq[(size_t)n * H2 + o] = aq;
    }
}

// ---------------- T6: A_pred[i][j] = sigmoid(sum_o w2[o]*leaky(P'[i,o]+Q[j,o])+bd2)
__global__ __launch_bounds__(256) void t6_dec(const float* __restrict__ Pp,
                                              const float* __restrict__ Qq,
                                              const float* __restrict__ Wd2,
                                              const float* __restrict__ bd2,
                                              float* __restrict__ Apred) {
    __shared__ float Qs[16][33];   // padded: conflict-free for [tx][o]
    __shared__ float Ws2[32];
    const int tid = threadIdx.x;
    const int j0 = blockIdx.x * 16, i0 = blockIdx.y * 16;
    const int tx = tid & 15, ty = tid >> 4;
    #pragma unroll
    for (int s = 0; s < 2; ++s) {
        int lin = tid + s * 256;            // 0..511
        int r = lin >> 5, c = lin & 31;
        Qs[r][c] = Qq[(size_t)(j0 + r) * H2 + c];
    }
    if (tid < 32) Ws2[tid] = Wd2[tid];
    float p[32];
    const float4* P4 = (const float4*)(Pp + (size_t)(i0 + ty) * H2);
    #pragma unroll
    for (int c = 0; c < 8; ++c) {
        float4 v = P4[c];
        p[c * 4] = v.x; p[c * 4 + 1] = v.y; p[c * 4 + 2] = v.z; p[c * 4 + 3] = v.w;
    }
    __syncthreads();
    float acc = 0.f;
    #pragma unroll
    for (int o = 0; o < 32; ++o) {
        float s = p[o] + Qs[tx][o];
        float lr = fmaf(0.01f, fminf(s, 0.f), fmaxf(s, 0.f));  // leaky_relu
        acc = fmaf(Ws2[o], lr, acc);
    }
    float logit = acc + bd2[0];
    float r = 1.f / (1.f + __expf(-logit));
    Apred[(size_t)(i0 + ty) * NNODE + (j0 + tx)] = r;
}

extern "C" void kernel_launch(void* const* d_in, const int* in_sizes, int n_in,
                              void* d_out, int out_size, void* d_ws, size_t ws_size,
                              hipStream_t stream) {
    const float* A   = (const float*)d_in[0];
    const float* X   = (const float*)d_in[1];
    const float* eps = (const float*)d_in[2];
    const float* W1  = (const float*)d_in[3];
    const float* b1  = (const float*)d_in[4];
    const float* Wmu = (const float*)d_in[5];
    const float* bmu = (const float*)d_in[6];
    const float* Wlv = (const float*)d_in[7];
    const float* blv = (const float*)d_in[8];
    const float* Wd1 = (const float*)d_in[9];
    const float* bd1 = (const float*)d_in[10];
    const float* Wd2 = (const float*)d_in[11];
    const float* bd2 = (const float*)d_in[12];
    float* out = (float*)d_out;
    char* ws = (char*)d_ws;

    // workspace carve (total ~3.9 MB)
    unsigned short* XWt = (unsigned short*)(ws);             // 256*2048*2  = 1,048,576
    float*          Hh  = (float*)(ws + 1048576);            // 2048*256*4  = 2,097,152
    unsigned short* Gt  = (unsigned short*)(ws + 3145728);   // 32*2048*2   =   131,072
    float*          M4  = (float*)(ws + 3276800);            // 2048*32*4   =   262,144
    float*          Pp  = (float*)(ws + 3538944);            // 2048*32*4
    float*          Qq  = (float*)(ws + 3801088);            // 2048*32*4

    float* out_mu = out + (size_t)NNODE * NNODE;
    float* out_lv = out_mu + NNODE * LLAT;

    hipMemsetAsync(M4, 0, (size_t)NNODE * H2 * sizeof(float), stream);

    t1_xw  <<<dim3(32, 4),   256, 0, stream>>>(W1, X, XWt);
    t2_gemm<<<dim3(32, 4),   256, 0, stream>>>(A, XWt, b1, Hh);
    t3_g   <<<256,           256, 0, stream>>>(Hh, Wmu, Wlv, Gt);
    t4_gemm<<<dim3(32, 8),   256, 0, stream>>>(A, Gt, M4);
    t5_z   <<<32,            256, 0, stream>>>(M4, bmu, blv, eps, Wd1, bd1,
                                               out_mu, out_lv, Pp, Qq);
    t6_dec <<<dim3(128, 128),256, 0, stream>>>(Pp, Qq, Wd2, bd2, out);
}

// Round 2
// 183.452 us; speedup vs baseline: 1.3900x; 1.3900x over previous
//
#include <hip/hip_runtime.h>

#define NNODE 2048
#define DD    512
#define HHID  256
#define LLAT  16
#define H2    32   // 2L

typedef __attribute__((ext_vector_type(8))) short  short8;
typedef __attribute__((ext_vector_type(4))) float  f32x4;

__device__ __forceinline__ unsigned short f2bf(float x) {
    unsigned int u = __float_as_uint(x);
    unsigned int r = (u + 0x7fffu + ((u >> 16) & 1u)) >> 16;  // RNE
    return (unsigned short)r;
}

// ---------------- T0: convert A, X, W1 to bf16 (grid-stride over float4) ---------
// ranges (in float4 units): A: [0, 1048576), X: [1048576, 1310720), W1: [1310720, 1343488)
__global__ __launch_bounds__(256) void t0_cvt(const float* __restrict__ A,
                                              const float* __restrict__ X,
                                              const float* __restrict__ W1,
                                              unsigned short* __restrict__ Abf,
                                              unsigned short* __restrict__ Xbf,
                                              unsigned short* __restrict__ W1bf) {
    const int NT = 1343488;
    for (int v = blockIdx.x * 256 + threadIdx.x; v < NT; v += gridDim.x * 256) {
        const float* src; unsigned short* dst; int off;
        if (v < 1048576)      { src = A;  dst = Abf;  off = v; }
        else if (v < 1310720) { src = X;  dst = Xbf;  off = v - 1048576; }
        else                  { src = W1; dst = W1bf; off = v - 1310720; }
        float4 f = ((const float4*)src)[off];
        short4 h;
        h.x = (short)f2bf(f.x); h.y = (short)f2bf(f.y);
        h.z = (short)f2bf(f.z); h.w = (short)f2bf(f.w);
        ((short4*)dst)[off] = h;
    }
}

// ---------------- T1: XWacc[h][n] += W1bf @ Xbf^T  (MFMA, splitK=4, atomic) ------
__global__ __launch_bounds__(256) void t1_mfma(const unsigned short* __restrict__ W1bf,
                                               const unsigned short* __restrict__ Xbf,
                                               float* __restrict__ XWacc) {
    __shared__ __align__(16) unsigned short Ab[64][40];
    __shared__ __align__(16) unsigned short Bb[64][40];
    const int tid = threadIdx.x;
    const int n0 = blockIdx.x * 64;     // node cols
    const int h0 = blockIdx.y * 64;     // hidden rows
    const int ks = blockIdx.z;          // 0..3, K chunk of 128
    const int lane = tid & 63, wave = tid >> 6;
    const int wm = wave >> 1, wn = wave & 1;
    const int lm = lane & 15, lk = (lane >> 4) * 8;
    const int sr = tid >> 2, sc = (tid & 3) * 8;
    f32x4 acc[2][2] = {};
    for (int it = 0; it < 4; ++it) {
        int kk = ks * 128 + it * 32;
        *(uint4*)&Ab[sr][sc] = *(const uint4*)(W1bf + (size_t)(h0 + sr) * DD + kk + sc);
        *(uint4*)&Bb[sr][sc] = *(const uint4*)(Xbf  + (size_t)(n0 + sr) * DD + kk + sc);
        __syncthreads();
        short8 a0 = *(const short8*)&Ab[wm * 32 + lm][lk];
        short8 a1 = *(const short8*)&Ab[wm * 32 + 16 + lm][lk];
        short8 b0 = *(const short8*)&Bb[wn * 32 + lm][lk];
        short8 b1 = *(const short8*)&Bb[wn * 32 + 16 + lm][lk];
        acc[0][0] = __builtin_amdgcn_mfma_f32_16x16x32_bf16(a0, b0, acc[0][0], 0, 0, 0);
        acc[0][1] = __builtin_amdgcn_mfma_f32_16x16x32_bf16(a0, b1, acc[0][1], 0, 0, 0);
        acc[1][0] = __builtin_amdgcn_mfma_f32_16x16x32_bf16(a1, b0, acc[1][0], 0, 0, 0);
        acc[1][1] = __builtin_amdgcn_mfma_f32_16x16x32_bf16(a1, b1, acc[1][1], 0, 0, 0);
        __syncthreads();
    }
    #pragma unroll
    for (int mi = 0; mi < 2; ++mi)
        #pragma unroll
        for (int ni = 0; ni < 2; ++ni)
            #pragma unroll
            for (int r = 0; r < 4; ++r) {
                int row = h0 + wm * 32 + mi * 16 + (lane >> 4) * 4 + r;
                int col = n0 + wn * 32 + ni * 16 + lm;
                atomicAdd(&XWacc[(size_t)row * NNODE + col], acc[mi][ni][r]);
            }
}

// ---------------- T1b: XWacc fp32 -> XWt bf16 ------------------------------------
__global__ __launch_bounds__(256) void t1b_cvt(const float* __restrict__ XWacc,
                                               unsigned short* __restrict__ XWt) {
    int v = blockIdx.x * 256 + threadIdx.x;      // 131072 float4 units
    float4 f = ((const float4*)XWacc)[v];
    short4 h;
    h.x = (short)f2bf(f.x); h.y = (short)f2bf(f.y);
    h.z = (short)f2bf(f.z); h.w = (short)f2bf(f.w);
    ((short4*)XWt)[v] = h;
}

// ---------------- T2: Hacc += A @ XW  (MFMA, splitK=8, atomic) -------------------
__global__ __launch_bounds__(256) void t2_mfma(const unsigned short* __restrict__ Abf,
                                               const unsigned short* __restrict__ XWt,
                                               float* __restrict__ Hacc) {
    __shared__ __align__(16) unsigned short Ab[64][40];
    __shared__ __align__(16) unsigned short Bb[64][40];
    const int tid = threadIdx.x;
    const int m0 = blockIdx.x * 64;     // node rows
    const int n0 = blockIdx.y * 64;     // hidden cols
    const int ks = blockIdx.z;          // 0..7, K chunk of 256
    const int lane = tid & 63, wave = tid >> 6;
    const int wm = wave >> 1, wn = wave & 1;
    const int lm = lane & 15, lk = (lane >> 4) * 8;
    const int sr = tid >> 2, sc = (tid & 3) * 8;
    f32x4 acc[2][2] = {};
    for (int it = 0; it < 8; ++it) {
        int kk = ks * 256 + it * 32;
        *(uint4*)&Ab[sr][sc] = *(const uint4*)(Abf + (size_t)(m0 + sr) * NNODE + kk + sc);
        *(uint4*)&Bb[sr][sc] = *(const uint4*)(XWt + (size_t)(n0 + sr) * NNODE + kk + sc);
        __syncthreads();
        short8 a0 = *(const short8*)&Ab[wm * 32 + lm][lk];
        short8 a1 = *(const short8*)&Ab[wm * 32 + 16 + lm][lk];
        short8 b0 = *(const short8*)&Bb[wn * 32 + lm][lk];
        short8 b1 = *(const short8*)&Bb[wn * 32 + 16 + lm][lk];
        acc[0][0] = __builtin_amdgcn_mfma_f32_16x16x32_bf16(a0, b0, acc[0][0], 0, 0, 0);
        acc[0][1] = __builtin_amdgcn_mfma_f32_16x16x32_bf16(a0, b1, acc[0][1], 0, 0, 0);
        acc[1][0] = __builtin_amdgcn_mfma_f32_16x16x32_bf16(a1, b0, acc[1][0], 0, 0, 0);
        acc[1][1] = __builtin_amdgcn_mfma_f32_16x16x32_bf16(a1, b1, acc[1][1], 0, 0, 0);
        __syncthreads();
    }
    #pragma unroll
    for (int mi = 0; mi < 2; ++mi)
        #pragma unroll
        for (int ni = 0; ni < 2; ++ni)
            #pragma unroll
            for (int r = 0; r < 4; ++r) {
                int row = m0 + wm * 32 + mi * 16 + (lane >> 4) * 4 + r;
                int col = n0 + wn * 32 + ni * 16 + lm;
                atomicAdd(&Hacc[(size_t)row * HHID + col], acc[mi][ni][r]);
            }
}

// ---------------- T3: Gt[j][n] = bf16( sum_d leaky(Hacc[n][d]+b1[d]) * Wcat[j][d] )
__global__ __launch_bounds__(256) void t3_g(const float* __restrict__ Hacc,
                                            const float* __restrict__ b1,
                                            const float* __restrict__ Wmu,
                                            const float* __restrict__ Wlv,
                                            unsigned short* __restrict__ Gt) {
    __shared__ float Hs[8][260];
    __shared__ float Ws[32][260];
    const int tid = threadIdx.x;
    const int n0 = blockIdx.x * 8;
    // stage Wcat (32 rows x 256)
    #pragma unroll
    for (int s = 0; s < 8; ++s) {
        int idx = tid + s * 256;            // float4 units, 0..2047
        int row = idx >> 6, c = (idx & 63) * 4;
        const float* src = (row < 16) ? (Wmu + (size_t)row * HHID)
                                      : (Wlv + (size_t)(row - 16) * HHID);
        *(float4*)&Ws[row][c] = *(const float4*)(src + c);
    }
    // stage 8 rows of activated H
    {
        int r = tid >> 5, seg = tid & 31;
        int d = seg * 8;
        #pragma unroll
        for (int t = 0; t < 2; ++t) {
            float4 h = *(const float4*)(Hacc + (size_t)(n0 + r) * HHID + d + t * 4);
            float4 b = *(const float4*)(b1 + d + t * 4);
            float4 o;
            float v;
            v = h.x + b.x; o.x = v >= 0.f ? v : 0.01f * v;
            v = h.y + b.y; o.y = v >= 0.f ? v : 0.01f * v;
            v = h.z + b.z; o.z = v >= 0.f ? v : 0.01f * v;
            v = h.w + b.w; o.w = v >= 0.f ? v : 0.01f * v;
            *(float4*)&Hs[r][d + t * 4] = o;
        }
    }
    __syncthreads();
    const int r = tid >> 5, j = tid & 31;
    float acc = 0.f;
    #pragma unroll 8
    for (int d4 = 0; d4 < 64; ++d4) {
        float4 a = *(const float4*)&Hs[r][d4 * 4];
        float4 b = *(const float4*)&Ws[j][d4 * 4];
        acc += a.x * b.x + a.y * b.y + a.z * b.z + a.w * b.w;
    }
    Gt[(size_t)j * NNODE + n0 + r] = f2bf(acc);
}

// ---------------- T4: M4 += A @ G  (MFMA, splitK=16, atomic) ---------------------
__global__ __launch_bounds__(256) void t4_mfma(const unsigned short* __restrict__ Abf,
                                               const unsigned short* __restrict__ Gt,
                                               float* __restrict__ M4) {
    __shared__ __align__(16) unsigned short Ab[64][40];
    __shared__ __align__(16) unsigned short Bb[32][40];
    const int tid = threadIdx.x;
    const int m0 = blockIdx.x * 64;
    const int ks = blockIdx.y;          // 0..15, K chunk of 128
    const int lane = tid & 63, wave = tid >> 6;
    const int lm = lane & 15, lk = (lane >> 4) * 8;
    const int sr = tid >> 2, sc = (tid & 3) * 8;
    f32x4 acc[2] = {};
    for (int it = 0; it < 4; ++it) {
        int kk = ks * 128 + it * 32;
        *(uint4*)&Ab[sr][sc] = *(const uint4*)(Abf + (size_t)(m0 + sr) * NNODE + kk + sc);
        if (tid < 128) {
            int row = tid >> 2, c = (tid & 3) * 8;
            *(uint4*)&Bb[row][c] = *(const uint4*)(Gt + (size_t)row * NNODE + kk + c);
        }
        __syncthreads();
        short8 a  = *(const short8*)&Ab[wave * 16 + lm][lk];
        short8 b0 = *(const short8*)&Bb[lm][lk];
        short8 b1 = *(const short8*)&Bb[16 + lm][lk];
        acc[0] = __builtin_amdgcn_mfma_f32_16x16x32_bf16(a, b0, acc[0], 0, 0, 0);
        acc[1] = __builtin_amdgcn_mfma_f32_16x16x32_bf16(a, b1, acc[1], 0, 0, 0);
        __syncthreads();
    }
    #pragma unroll
    for (int ni = 0; ni < 2; ++ni)
        #pragma unroll
        for (int r = 0; r < 4; ++r) {
            int row = m0 + wave * 16 + (lane >> 4) * 4 + r;
            int col = ni * 16 + lm;
            atomicAdd(&M4[(size_t)row * H2 + col], acc[ni][r]);
        }
}

// ---------------- T5: mu/logvar out, Z, P' = Z@Wd1[:,:L]^T + bd1, Q --------------
__global__ __launch_bounds__(256) void t5_z(const float* __restrict__ M4,
                                            const float* __restrict__ bmu,
                                            const float* __restrict__ blv,
                                            const float* __restrict__ eps,
                                            const float* __restrict__ Wd1,
                                            const float* __restrict__ bd1,
                                            float* __restrict__ out_mu,
                                            float* __restrict__ out_lv,
                                            float* __restrict__ Pp,
                                            float* __restrict__ Qq) {
    __shared__ float Zs[64][16];
    const int tid = threadIdx.x;
    const int n0 = blockIdx.x * 64;
    #pragma unroll
    for (int p = 0; p < 4; ++p) {
        int idx = tid + p * 256;            // 0..1023
        int nl = idx >> 4, l = idx & 15;
        int n = n0 + nl;
        float m  = M4[(size_t)n * H2 + l]      + bmu[l];
        float lv = M4[(size_t)n * H2 + 16 + l] + blv[l];
        out_mu[(size_t)n * LLAT + l] = m;
        out_lv[(size_t)n * LLAT + l] = lv;
        Zs[nl][l] = m + eps[(size_t)n * LLAT + l] * __expf(0.5f * lv);
    }
    __syncthreads();
    #pragma unroll
    for (int p = 0; p < 8; ++p) {
        int idx = tid + p * 256;            // 0..2047
        int nl = idx >> 5, o = idx & 31;
        int n = n0 + nl;
        float ap = bd1[o], aq = 0.f;
        #pragma unroll
        for (int l = 0; l < 16; ++l) {
            float z = Zs[nl][l];
            ap = fmaf(z, Wd1[o * H2 + l],      ap);
            aq = fmaf(z, Wd1[o * H2 + 16 + l], aq);
        }
        Pp[(size_t)n * H2 + o] = ap;
        Qq[(size_t)n * H2 + o] = aq;
    }
}

// ---------------- T6: A_pred[i][j] = sigmoid(sum_o w2[o]*leaky(P'[i,o]+Q[j,o])+bd2)
// tile: 16 i-rows x 64 j-cols; thread = (i, 4 j's)
__global__ __launch_bounds__(256) void t6_dec(const float* __restrict__ Pp,
                                              const float* __restrict__ Qq,
                                              const float* __restrict__ Wd2,
                                              const float* __restrict__ bd2,
                                              float* __restrict__ Apred) {
    __shared__ float Qt[32][68];   // transposed Q tile, padded
    __shared__ float Ws2[32];
    const int tid = threadIdx.x;
    const int j0 = blockIdx.x * 64, i0 = blockIdx.y * 16;
    #pragma unroll
    for (int s = 0; s < 8; ++s) {
        int idx = tid + s * 256;            // 0..2047
        int j = idx >> 5, o = idx & 31;
        Qt[o][j] = Qq[(size_t)(j0 + j) * H2 + o];
    }
    if (tid < 32) Ws2[tid] = Wd2[tid];
    const int i = i0 + (tid >> 4);
    const int jq = tid & 15;
    float p[32];
    const float4* P4 = (const float4*)(Pp + (size_t)i * H2);
    #pragma unroll
    for (int c = 0; c < 8; ++c) {
        float4 v = P4[c];
        p[c * 4] = v.x; p[c * 4 + 1] = v.y; p[c * 4 + 2] = v.z; p[c * 4 + 3] = v.w;
    }
    __syncthreads();
    f32x4 acc = {0.f, 0.f, 0.f, 0.f};
    #pragma unroll
    for (int o = 0; o < 32; ++o) {
        float4 q = *(const float4*)&Qt[o][jq * 4];
        float w = Ws2[o], po = p[o];
        float s0 = po + q.x, s1 = po + q.y, s2 = po + q.z, s3 = po + q.w;
        acc[0] = fmaf(w, fmaf(0.01f, fminf(s0, 0.f), fmaxf(s0, 0.f)), acc[0]);
        acc[1] = fmaf(w, fmaf(0.01f, fminf(s1, 0.f), fmaxf(s1, 0.f)), acc[1]);
        acc[2] = fmaf(w, fmaf(0.01f, fminf(s2, 0.f), fmaxf(s2, 0.f)), acc[2]);
        acc[3] = fmaf(w, fmaf(0.01f, fminf(s3, 0.f), fmaxf(s3, 0.f)), acc[3]);
    }
    float b = bd2[0];
    float4 r;
    r.x = 1.f / (1.f + __expf(-(acc[0] + b)));
    r.y = 1.f / (1.f + __expf(-(acc[1] + b)));
    r.z = 1.f / (1.f + __expf(-(acc[2] + b)));
    r.w = 1.f / (1.f + __expf(-(acc[3] + b)));
    *(float4*)(Apred + (size_t)i * NNODE + j0 + jq * 4) = r;
}

extern "C" void kernel_launch(void* const* d_in, const int* in_sizes, int n_in,
                              void* d_out, int out_size, void* d_ws, size_t ws_size,
                              hipStream_t stream) {
    const float* A   = (const float*)d_in[0];
    const float* X   = (const float*)d_in[1];
    const float* eps = (const float*)d_in[2];
    const float* W1  = (const float*)d_in[3];
    const float* b1  = (const float*)d_in[4];
    const float* Wmu = (const float*)d_in[5];
    const float* bmu = (const float*)d_in[6];
    const float* Wlv = (const float*)d_in[7];
    const float* blv = (const float*)d_in[8];
    const float* Wd1 = (const float*)d_in[9];
    const float* bd1 = (const float*)d_in[10];
    const float* Wd2 = (const float*)d_in[11];
    const float* bd2 = (const float*)d_in[12];
    float* out = (float*)d_out;
    char* ws = (char*)d_ws;

    // workspace carve (~16.9 MB)
    unsigned short* Abf   = (unsigned short*)(ws);              //  8,388,608
    unsigned short* Xbf   = (unsigned short*)(ws + 8388608);    //  2,097,152
    unsigned short* W1bf  = (unsigned short*)(ws + 10485760);   //    262,144
    float*          XWacc = (float*)(ws + 10747904);            //  2,097,152
    unsigned short* XWt   = (unsigned short*)(ws + 12845056);   //  1,048,576
    float*          Hacc  = (float*)(ws + 13893632);            //  2,097,152
    unsigned short* Gt    = (unsigned short*)(ws + 15990784);   //    131,072
    float*          M4    = (float*)(ws + 16121856);            //    262,144
    float*          Pp    = (float*)(ws + 16384000);            //    262,144
    float*          Qq    = (float*)(ws + 16646144);            //    262,144

    float* out_mu = out + (size_t)NNODE * NNODE;
    float* out_lv = out_mu + NNODE * LLAT;

    hipMemsetAsync(XWacc, 0, 2097152, stream);
    hipMemsetAsync(Hacc,  0, 2097152, stream);
    hipMemsetAsync(M4,    0, 262144,  stream);

    t0_cvt <<<2048,              256, 0, stream>>>(A, X, W1, Abf, Xbf, W1bf);
    t1_mfma<<<dim3(32, 4, 4),    256, 0, stream>>>(W1bf, Xbf, XWacc);
    t1b_cvt<<<512,               256, 0, stream>>>(XWacc, XWt);
    t2_mfma<<<dim3(32, 4, 8),    256, 0, stream>>>(Abf, XWt, Hacc);
    t3_g   <<<256,               256, 0, stream>>>(Hacc, b1, Wmu, Wlv, Gt);
    t4_mfma<<<dim3(32, 16),      256, 0, stream>>>(Abf, Gt, M4);
    t5_z   <<<32,                256, 0, stream>>>(M4, bmu, blv, eps, Wd1, bd1,
                                                   out_mu, out_lv, Pp, Qq);
    t6_dec <<<dim3(32, 128),     256, 0, stream>>>(Pp, Qq, Wd2, bd2, out);
}

// Round 3
// 147.801 us; speedup vs baseline: 1.7253x; 1.2412x over previous
//
#include <hip/hip_runtime.h>

#define NNODE 2048
#define DD    512
#define HHID  256
#define LLAT  16
#define H2    32   // 2L

typedef __attribute__((ext_vector_type(8))) short  short8;
typedef __attribute__((ext_vector_type(4))) float  f32x4;

__device__ __forceinline__ unsigned short f2bf(float x) {
    unsigned int u = __float_as_uint(x);
    unsigned int r = (u + 0x7fffu + ((u >> 16) & 1u)) >> 16;  // RNE
    return (unsigned short)r;
}
__device__ __forceinline__ float bf2f(unsigned short u) {
    return __uint_as_float(((unsigned int)u) << 16);
}

// ---------------- T0: convert A, X, W1 to bf16 (grid-stride over float4) ---------
__global__ __launch_bounds__(256) void t0_cvt(const float* __restrict__ A,
                                              const float* __restrict__ X,
                                              const float* __restrict__ W1,
                                              unsigned short* __restrict__ Abf,
                                              unsigned short* __restrict__ Xbf,
                                              unsigned short* __restrict__ W1bf) {
    const int NT = 1343488;   // 1048576 (A) + 262144 (X) + 32768 (W1) float4 units
    for (int v = blockIdx.x * 256 + threadIdx.x; v < NT; v += gridDim.x * 256) {
        const float* src; unsigned short* dst; int off;
        if (v < 1048576)      { src = A;  dst = Abf;  off = v; }
        else if (v < 1310720) { src = X;  dst = Xbf;  off = v - 1048576; }
        else                  { src = W1; dst = W1bf; off = v - 1310720; }
        float4 f = ((const float4*)src)[off];
        short4 h;
        h.x = (short)f2bf(f.x); h.y = (short)f2bf(f.y);
        h.z = (short)f2bf(f.z); h.w = (short)f2bf(f.w);
        ((short4*)dst)[off] = h;
    }
}

// ---------------- T1: XWp[s][h][n] = partial W1bf @ Xbf^T  (MFMA, splitK=4) ------
__global__ __launch_bounds__(256) void t1_mfma(const unsigned short* __restrict__ W1bf,
                                               const unsigned short* __restrict__ Xbf,
                                               float* __restrict__ XWp) {
    __shared__ __align__(16) unsigned short Ab[64][40];
    __shared__ __align__(16) unsigned short Bb[64][40];
    const int tid = threadIdx.x;
    const int n0 = blockIdx.x * 64;     // node cols
    const int h0 = blockIdx.y * 64;     // hidden rows
    const int ks = blockIdx.z;          // 0..3, K chunk of 128
    const int lane = tid & 63, wave = tid >> 6;
    const int wm = wave >> 1, wn = wave & 1;
    const int lm = lane & 15, lk = (lane >> 4) * 8;
    const int sr = tid >> 2, sc = (tid & 3) * 8;
    f32x4 acc[2][2] = {};
    for (int it = 0; it < 4; ++it) {
        int kk = ks * 128 + it * 32;
        *(uint4*)&Ab[sr][sc] = *(const uint4*)(W1bf + (size_t)(h0 + sr) * DD + kk + sc);
        *(uint4*)&Bb[sr][sc] = *(const uint4*)(Xbf  + (size_t)(n0 + sr) * DD + kk + sc);
        __syncthreads();
        short8 a0 = *(const short8*)&Ab[wm * 32 + lm][lk];
        short8 a1 = *(const short8*)&Ab[wm * 32 + 16 + lm][lk];
        short8 b0 = *(const short8*)&Bb[wn * 32 + lm][lk];
        short8 b1 = *(const short8*)&Bb[wn * 32 + 16 + lm][lk];
        acc[0][0] = __builtin_amdgcn_mfma_f32_16x16x32_bf16(a0, b0, acc[0][0], 0, 0, 0);
        acc[0][1] = __builtin_amdgcn_mfma_f32_16x16x32_bf16(a0, b1, acc[0][1], 0, 0, 0);
        acc[1][0] = __builtin_amdgcn_mfma_f32_16x16x32_bf16(a1, b0, acc[1][0], 0, 0, 0);
        acc[1][1] = __builtin_amdgcn_mfma_f32_16x16x32_bf16(a1, b1, acc[1][1], 0, 0, 0);
        __syncthreads();
    }
    float* outp = XWp + (size_t)ks * 524288;
    #pragma unroll
    for (int mi = 0; mi < 2; ++mi)
        #pragma unroll
        for (int ni = 0; ni < 2; ++ni)
            #pragma unroll
            for (int r = 0; r < 4; ++r) {
                int row = h0 + wm * 32 + mi * 16 + (lane >> 4) * 4 + r;
                int col = n0 + wn * 32 + ni * 16 + lm;
                outp[(size_t)row * NNODE + col] = acc[mi][ni][r];
            }
}

// ---------------- T1r: XWt = bf16(sum_s XWp[s]) ----------------------------------
__global__ __launch_bounds__(256) void t1r(const float* __restrict__ XWp,
                                           unsigned short* __restrict__ XWt) {
    int v = blockIdx.x * 256 + threadIdx.x;      // 131072 float4 units
    const float4* p = (const float4*)XWp;
    float4 a = p[v];
    float4 b = p[v + 131072];
    float4 c = p[v + 262144];
    float4 d = p[v + 393216];
    float4 s;
    s.x = (a.x + b.x) + (c.x + d.x);
    s.y = (a.y + b.y) + (c.y + d.y);
    s.z = (a.z + b.z) + (c.z + d.z);
    s.w = (a.w + b.w) + (c.w + d.w);
    short4 h;
    h.x = (short)f2bf(s.x); h.y = (short)f2bf(s.y);
    h.z = (short)f2bf(s.z); h.w = (short)f2bf(s.w);
    ((short4*)XWt)[v] = h;
}

// ---------------- T2: Hp[s][m][d] = partial A @ XW  (MFMA, splitK=4) -------------
__global__ __launch_bounds__(256) void t2_mfma(const unsigned short* __restrict__ Abf,
                                               const unsigned short* __restrict__ XWt,
                                               float* __restrict__ Hp) {
    __shared__ __align__(16) unsigned short Ab[64][40];
    __shared__ __align__(16) unsigned short Bb[64][40];
    const int tid = threadIdx.x;
    const int m0 = blockIdx.x * 64;     // node rows
    const int n0 = blockIdx.y * 64;     // hidden cols
    const int ks = blockIdx.z;          // 0..3, K chunk of 512
    const int lane = tid & 63, wave = tid >> 6;
    const int wm = wave >> 1, wn = wave & 1;
    const int lm = lane & 15, lk = (lane >> 4) * 8;
    const int sr = tid >> 2, sc = (tid & 3) * 8;
    f32x4 acc[2][2] = {};
    for (int it = 0; it < 16; ++it) {
        int kk = ks * 512 + it * 32;
        *(uint4*)&Ab[sr][sc] = *(const uint4*)(Abf + (size_t)(m0 + sr) * NNODE + kk + sc);
        *(uint4*)&Bb[sr][sc] = *(const uint4*)(XWt + (size_t)(n0 + sr) * NNODE + kk + sc);
        __syncthreads();
        short8 a0 = *(const short8*)&Ab[wm * 32 + lm][lk];
        short8 a1 = *(const short8*)&Ab[wm * 32 + 16 + lm][lk];
        short8 b0 = *(const short8*)&Bb[wn * 32 + lm][lk];
        short8 b1 = *(const short8*)&Bb[wn * 32 + 16 + lm][lk];
        acc[0][0] = __builtin_amdgcn_mfma_f32_16x16x32_bf16(a0, b0, acc[0][0], 0, 0, 0);
        acc[0][1] = __builtin_amdgcn_mfma_f32_16x16x32_bf16(a0, b1, acc[0][1], 0, 0, 0);
        acc[1][0] = __builtin_amdgcn_mfma_f32_16x16x32_bf16(a1, b0, acc[1][0], 0, 0, 0);
        acc[1][1] = __builtin_amdgcn_mfma_f32_16x16x32_bf16(a1, b1, acc[1][1], 0, 0, 0);
        __syncthreads();
    }
    float* outp = Hp + (size_t)ks * 524288;
    #pragma unroll
    for (int mi = 0; mi < 2; ++mi)
        #pragma unroll
        for (int ni = 0; ni < 2; ++ni)
            #pragma unroll
            for (int r = 0; r < 4; ++r) {
                int row = m0 + wm * 32 + mi * 16 + (lane >> 4) * 4 + r;
                int col = n0 + wn * 32 + ni * 16 + lm;
                outp[(size_t)row * HHID + col] = acc[mi][ni][r];
            }
}

// ---------------- T2r: Hbf = bf16(leaky(sum_s Hp[s] + b1)) -----------------------
__global__ __launch_bounds__(256) void t2r(const float* __restrict__ Hp,
                                           const float* __restrict__ b1,
                                           unsigned short* __restrict__ Hbf) {
    int v = blockIdx.x * 256 + threadIdx.x;      // 131072 float4 units
    const float4* p = (const float4*)Hp;
    float4 a = p[v];
    float4 b = p[v + 131072];
    float4 c = p[v + 262144];
    float4 d = p[v + 393216];
    int dcol = (v & 63) * 4;
    float4 bb = *(const float4*)(b1 + dcol);
    float4 s;
    s.x = (a.x + b.x) + (c.x + d.x) + bb.x;
    s.y = (a.y + b.y) + (c.y + d.y) + bb.y;
    s.z = (a.z + b.z) + (c.z + d.z) + bb.z;
    s.w = (a.w + b.w) + (c.w + d.w) + bb.w;
    s.x = s.x >= 0.f ? s.x : 0.01f * s.x;
    s.y = s.y >= 0.f ? s.y : 0.01f * s.y;
    s.z = s.z >= 0.f ? s.z : 0.01f * s.z;
    s.w = s.w >= 0.f ? s.w : 0.01f * s.w;
    short4 h;
    h.x = (short)f2bf(s.x); h.y = (short)f2bf(s.y);
    h.z = (short)f2bf(s.z); h.w = (short)f2bf(s.w);
    ((short4*)Hbf)[v] = h;
}

// ---------------- T3: Gt[j][n] = bf16( sum_d Hbf[n][d] * Wcat[j][d] ) ------------
__global__ __launch_bounds__(256) void t3_g(const unsigned short* __restrict__ Hbf,
                                            const float* __restrict__ Wmu,
                                            const float* __restrict__ Wlv,
                                            unsigned short* __restrict__ Gt) {
    __shared__ float Hs[8][260];
    __shared__ float Ws[32][260];
    const int tid = threadIdx.x;
    const int n0 = blockIdx.x * 8;
    // stage Wcat (32 rows x 256)
    #pragma unroll
    for (int s = 0; s < 8; ++s) {
        int idx = tid + s * 256;            // float4 units, 0..2047
        int row = idx >> 6, c = (idx & 63) * 4;
        const float* src = (row < 16) ? (Wmu + (size_t)row * HHID)
                                      : (Wlv + (size_t)(row - 16) * HHID);
        *(float4*)&Ws[row][c] = *(const float4*)(src + c);
    }
    // stage 8 rows of activated H (bf16 -> f32)
    {
        int r = tid >> 5, seg = tid & 31;
        int d = seg * 8;
        ushort4 u0 = *(const ushort4*)(Hbf + (size_t)(n0 + r) * HHID + d);
        ushort4 u1 = *(const ushort4*)(Hbf + (size_t)(n0 + r) * HHID + d + 4);
        Hs[r][d + 0] = bf2f(u0.x); Hs[r][d + 1] = bf2f(u0.y);
        Hs[r][d + 2] = bf2f(u0.z); Hs[r][d + 3] = bf2f(u0.w);
        Hs[r][d + 4] = bf2f(u1.x); Hs[r][d + 5] = bf2f(u1.y);
        Hs[r][d + 6] = bf2f(u1.z); Hs[r][d + 7] = bf2f(u1.w);
    }
    __syncthreads();
    const int r = tid >> 5, j = tid & 31;
    float acc = 0.f;
    #pragma unroll 8
    for (int d4 = 0; d4 < 64; ++d4) {
        float4 a = *(const float4*)&Hs[r][d4 * 4];
        float4 b = *(const float4*)&Ws[j][d4 * 4];
        acc += a.x * b.x + a.y * b.y + a.z * b.z + a.w * b.w;
    }
    Gt[(size_t)j * NNODE + n0 + r] = f2bf(acc);
}

// ---------------- T4: Mp[s][m][c] = partial A @ G  (MFMA, splitK=8) --------------
__global__ __launch_bounds__(256) void t4_mfma(const unsigned short* __restrict__ Abf,
                                               const unsigned short* __restrict__ Gt,
                                               float* __restrict__ Mp) {
    __shared__ __align__(16) unsigned short Ab[64][40];
    __shared__ __align__(16) unsigned short Bb[32][40];
    const int tid = threadIdx.x;
    const int m0 = blockIdx.x * 64;
    const int ks = blockIdx.y;          // 0..7, K chunk of 256
    const int lane = tid & 63, wave = tid >> 6;
    const int lm = lane & 15, lk = (lane >> 4) * 8;
    const int sr = tid >> 2, sc = (tid & 3) * 8;
    f32x4 acc[2] = {};
    for (int it = 0; it < 8; ++it) {
        int kk = ks * 256 + it * 32;
        *(uint4*)&Ab[sr][sc] = *(const uint4*)(Abf + (size_t)(m0 + sr) * NNODE + kk + sc);
        if (tid < 128) {
            int row = tid >> 2, c = (tid & 3) * 8;
            *(uint4*)&Bb[row][c] = *(const uint4*)(Gt + (size_t)row * NNODE + kk + c);
        }
        __syncthreads();
        short8 a  = *(const short8*)&Ab[wave * 16 + lm][lk];
        short8 b0 = *(const short8*)&Bb[lm][lk];
        short8 b1 = *(const short8*)&Bb[16 + lm][lk];
        acc[0] = __builtin_amdgcn_mfma_f32_16x16x32_bf16(a, b0, acc[0], 0, 0, 0);
        acc[1] = __builtin_amdgcn_mfma_f32_16x16x32_bf16(a, b1, acc[1], 0, 0, 0);
        __syncthreads();
    }
    float* outp = Mp + (size_t)ks * 65536;
    #pragma unroll
    for (int ni = 0; ni < 2; ++ni)
        #pragma unroll
        for (int r = 0; r < 4; ++r) {
            int row = m0 + wave * 16 + (lane >> 4) * 4 + r;
            int col = ni * 16 + lm;
            outp[(size_t)row * H2 + col] = acc[ni][r];
        }
}

// ---------------- T5: reduce Mp; mu/logvar out; Z; P' and Q ----------------------
__global__ __launch_bounds__(256) void t5_z(const float* __restrict__ Mp,
                                            const float* __restrict__ bmu,
                                            const float* __restrict__ blv,
                                            const float* __restrict__ eps,
                                            const float* __restrict__ Wd1,
                                            const float* __restrict__ bd1,
                                            float* __restrict__ out_mu,
                                            float* __restrict__ out_lv,
                                            float* __restrict__ Pp,
                                            float* __restrict__ Qq) {
    __shared__ float Zs[16][16];
    const int tid = threadIdx.x;
    const int n0 = blockIdx.x * 16;
    {
        int nl = tid >> 4, l = tid & 15;
        int n = n0 + nl;
        float m = bmu[l], lv = blv[l];
        #pragma unroll
        for (int s = 0; s < 8; ++s) {
            m  += Mp[(size_t)s * 65536 + (size_t)n * H2 + l];
            lv += Mp[(size_t)s * 65536 + (size_t)n * H2 + 16 + l];
        }
        out_mu[(size_t)n * LLAT + l] = m;
        out_lv[(size_t)n * LLAT + l] = lv;
        Zs[nl][l] = m + eps[(size_t)n * LLAT + l] * __expf(0.5f * lv);
    }
    __syncthreads();
    #pragma unroll
    for (int p = 0; p < 2; ++p) {
        int idx = tid + p * 256;            // 0..511
        int nl = idx >> 5, o = idx & 31;
        int n = n0 + nl;
        float ap = bd1[o], aq = 0.f;
        #pragma unroll
        for (int l = 0; l < 16; ++l) {
            float z = Zs[nl][l];
            ap = fmaf(z, Wd1[o * H2 + l],      ap);
            aq = fmaf(z, Wd1[o * H2 + 16 + l], aq);
        }
        Pp[(size_t)n * H2 + o] = ap;
        Qq[(size_t)n * H2 + o] = aq;
    }
}

// ---------------- T6: A_pred[i][j] = sigmoid(sum_o w2[o]*leaky(P'[i,o]+Q[j,o])+bd2)
__global__ __launch_bounds__(256) void t6_dec(const float* __restrict__ Pp,
                                              const float* __restrict__ Qq,
                                              const float* __restrict__ Wd2,
                                              const float* __restrict__ bd2,
                                              float* __restrict__ Apred) {
    __shared__ float Qt[32][68];   // transposed Q tile, padded
    __shared__ float Ws2[32];
    const int tid = threadIdx.x;
    const int j0 = blockIdx.x * 64, i0 = blockIdx.y * 16;
    #pragma unroll
    for (int s = 0; s < 8; ++s) {
        int idx = tid + s * 256;            // 0..2047
        int j = idx >> 5, o = idx & 31;
        Qt[o][j] = Qq[(size_t)(j0 + j) * H2 + o];
    }
    if (tid < 32) Ws2[tid] = Wd2[tid];
    const int i = i0 + (tid >> 4);
    const int jq = tid & 15;
    float p[32];
    const float4* P4 = (const float4*)(Pp + (size_t)i * H2);
    #pragma unroll
    for (int c = 0; c < 8; ++c) {
        float4 v = P4[c];
        p[c * 4] = v.x; p[c * 4 + 1] = v.y; p[c * 4 + 2] = v.z; p[c * 4 + 3] = v.w;
    }
    __syncthreads();
    f32x4 acc = {0.f, 0.f, 0.f, 0.f};
    #pragma unroll
    for (int o = 0; o < 32; ++o) {
        float4 q = *(const float4*)&Qt[o][jq * 4];
        float w = Ws2[o], po = p[o];
        float s0 = po + q.x, s1 = po + q.y, s2 = po + q.z, s3 = po + q.w;
        acc[0] = fmaf(w, fmaf(0.01f, fminf(s0, 0.f), fmaxf(s0, 0.f)), acc[0]);
        acc[1] = fmaf(w, fmaf(0.01f, fminf(s1, 0.f), fmaxf(s1, 0.f)), acc[1]);
        acc[2] = fmaf(w, fmaf(0.01f, fminf(s2, 0.f), fmaxf(s2, 0.f)), acc[2]);
        acc[3] = fmaf(w, fmaf(0.01f, fminf(s3, 0.f), fmaxf(s3, 0.f)), acc[3]);
    }
    float b = bd2[0];
    float4 r;
    r.x = 1.f / (1.f + __expf(-(acc[0] + b)));
    r.y = 1.f / (1.f + __expf(-(acc[1] + b)));
    r.z = 1.f / (1.f + __expf(-(acc[2] + b)));
    r.w = 1.f / (1.f + __expf(-(acc[3] + b)));
    *(float4*)(Apred + (size_t)i * NNODE + j0 + jq * 4) = r;
}

extern "C" void kernel_launch(void* const* d_in, const int* in_sizes, int n_in,
                              void* d_out, int out_size, void* d_ws, size_t ws_size,
                              hipStream_t stream) {
    const float* A   = (const float*)d_in[0];
    const float* X   = (const float*)d_in[1];
    const float* eps = (const float*)d_in[2];
    const float* W1  = (const float*)d_in[3];
    const float* b1  = (const float*)d_in[4];
    const float* Wmu = (const float*)d_in[5];
    const float* bmu = (const float*)d_in[6];
    const float* Wlv = (const float*)d_in[7];
    const float* blv = (const float*)d_in[8];
    const float* Wd1 = (const float*)d_in[9];
    const float* bd1 = (const float*)d_in[10];
    const float* Wd2 = (const float*)d_in[11];
    const float* bd2 = (const float*)d_in[12];
    float* out = (float*)d_out;
    char* ws = (char*)d_ws;

    // workspace carve (~32.4 MB), all partial buffers fully overwritten each call
    unsigned short* Abf  = (unsigned short*)(ws);               //  8,388,608
    unsigned short* Xbf  = (unsigned short*)(ws + 8388608);     //  2,097,152
    unsigned short* W1bf = (unsigned short*)(ws + 10485760);    //    262,144
    float*          XWp  = (float*)(ws + 10747904);             //  8,388,608 (4 x 2MB)
    unsigned short* XWt  = (unsigned short*)(ws + 19136512);    //  1,048,576
    float*          Hp   = (float*)(ws + 20185088);             //  8,388,608 (4 x 2MB)
    unsigned short* Hbf  = (unsigned short*)(ws + 28573696);    //  1,048,576
    unsigned short* Gt   = (unsigned short*)(ws + 29622272);    //    131,072
    float*          Mp   = (float*)(ws + 29753344);             //  2,097,152 (8 x 256KB)
    float*          Pp   = (float*)(ws + 31850496);             //    262,144
    float*          Qq   = (float*)(ws + 32112640);             //    262,144

    float* out_mu = out + (size_t)NNODE * NNODE;
    float* out_lv = out_mu + NNODE * LLAT;

    t0_cvt <<<2048,            256, 0, stream>>>(A, X, W1, Abf, Xbf, W1bf);
    t1_mfma<<<dim3(32, 4, 4),  256, 0, stream>>>(W1bf, Xbf, XWp);
    t1r    <<<512,             256, 0, stream>>>(XWp, XWt);
    t2_mfma<<<dim3(32, 4, 4),  256, 0, stream>>>(Abf, XWt, Hp);
    t2r    <<<512,             256, 0, stream>>>(Hp, b1, Hbf);
    t3_g   <<<256,             256, 0, stream>>>(Hbf, Wmu, Wlv, Gt);
    t4_mfma<<<dim3(32, 8),     256, 0, stream>>>(Abf, Gt, Mp);
    t5_z   <<<128,             256, 0, stream>>>(Mp, bmu, blv, eps, Wd1, bd1,
                                                 out_mu, out_lv, Pp, Qq);
    t6_dec <<<dim3(32, 128),   256, 0, stream>>>(Pp, Qq, Wd2, bd2, out);
}